// Round 6
// baseline (384.004 us; speedup 1.0000x reference)
//
#include <hip/hip_runtime.h>
#include <cstdint>
#include <cstddef>

#define N_    16
#define DIM_  2048
#define RF_   256
#define PN_   64
#define TOPK_ 10
#define HW_   128
#define KFULL (DIM_*HW_)   /* 262144 */
#define KMV   (TOPK_*RF_)  /* 2560 */

#define AS1 __attribute__((address_space(1)))
#define AS3 __attribute__((address_space(3)))

typedef __attribute__((ext_vector_type(8))) short bf16x8;
typedef __attribute__((ext_vector_type(4))) float f32x4;
typedef __attribute__((ext_vector_type(8))) unsigned short u16x8;

__device__ __forceinline__ unsigned short f2bf(float f) {
  unsigned u = __builtin_bit_cast(unsigned, f);
  unsigned r = (u + 0x7FFFu + ((u >> 16) & 1u)) >> 16;
  return (unsigned short)r;
}

// ---------------------------------------------------------------------------
// Weight convert fp32 [O][C] -> bf16 k-quad-major W'[C/8][O][8], LDS-tiled so
// BOTH sides are coalesced. Tile = 64 o x 32 cg cells (16B/cell).
// Also zero-inits flags (dsum region kept for layout compat).
// Grid: 864 tiles (32 + 320 + 256 + 256).
// ---------------------------------------------------------------------------
__global__ __launch_bounds__(256)
void cvt_all_kernel(const float* __restrict__ s0, const float* __restrict__ s1,
                    const float* __restrict__ s2, const float* __restrict__ s3,
                    unsigned short* __restrict__ d0, unsigned short* __restrict__ d1,
                    unsigned short* __restrict__ d2, unsigned short* __restrict__ d3,
                    float* __restrict__ dsum) {
  __shared__ u16x8 tile[32][65];   // [cg_local][o_local], +1 cell pad
  const int t = threadIdx.x;
  int gid = blockIdx.x * 256 + t;
  if (gid < 1152) dsum[gid] = 0.f;   // dsum (1088) + flags (64), contiguous

  int bid = blockIdx.x;
  const float* s; unsigned short* d; int O, CG, tb;
  if (bid < 32)       { s = s0; d = d0; O = RF_;  CG = DIM_ / 8; tb = bid; }
  else if (bid < 352) { s = s1; d = d1; O = DIM_; CG = KMV  / 8; tb = bid - 32; }
  else if (bid < 608) { s = s2; d = d2; O = DIM_; CG = DIM_ / 8; tb = bid - 352; }
  else                { s = s3; d = d3; O = DIM_; CG = DIM_ / 8; tb = bid - 608; }
  const int nCgT = CG / 32;
  const int o0  = (tb / nCgT) * 64;
  const int cg0 = (tb % nCgT) * 32;
  const size_t C = (size_t)CG * 8;

  // read + convert: idx = i*256+t -> o_l = idx>>5, cg_l = idx&31
#pragma unroll
  for (int i = 0; i < 8; ++i) {
    int idx = i * 256 + t, ol = idx >> 5, cg = idx & 31;
    const float* sp = s + (size_t)(o0 + ol) * C + (size_t)(cg0 + cg) * 8;
    float4 a = *(const float4*)sp;
    float4 b = *(const float4*)(sp + 4);
    u16x8 pk;
    pk[0] = f2bf(a.x); pk[1] = f2bf(a.y); pk[2] = f2bf(a.z); pk[3] = f2bf(a.w);
    pk[4] = f2bf(b.x); pk[5] = f2bf(b.y); pk[6] = f2bf(b.z); pk[7] = f2bf(b.w);
    tile[cg][ol] = pk;
  }
  __syncthreads();
  // write: idx -> cg_l = idx>>6, o_l = idx&63
#pragma unroll
  for (int i = 0; i < 8; ++i) {
    int idx = i * 256 + t, cg = idx >> 6, ol = idx & 63;
    *(u16x8*)(d + (size_t)(cg0 + cg) * ((size_t)O * 8) + (size_t)(o0 + ol) * 8) =
        tile[cg][ol];
  }
}

// ---------------------------------------------------------------------------
// proto [64][2048][128] fp32 -> protoT' [64][kq=256][s=128][8] bf16
// (k-quad-major). ||p||^2 partial: block-reduce then ONE PLAIN STORE per
// block into pnorm_part[cb][p]; select_kernel sums the 64 partials.
// ---------------------------------------------------------------------------
__global__ __launch_bounds__(256)
void transpose_proto_kernel(const float* __restrict__ src,
                            unsigned short* __restrict__ dst,
                            float* __restrict__ pnorm_part) {
  __shared__ float tile[32][129];
  __shared__ float ssq[4];
  const int p = blockIdx.x;
  const int c0 = blockIdx.y * 32;
  const int t = threadIdx.x;
  const float* sp = src + ((size_t)p * DIM_ + c0) * HW_;
  float sq = 0.f;
#pragma unroll
  for (int i = 0; i < 4; ++i) {
    int g = i * 256 + t;
    int ci = g >> 5, s4 = g & 31;
    float4 v = *(const float4*)(sp + (size_t)ci * HW_ + s4 * 4);
    sq += v.x * v.x + v.y * v.y + v.z * v.z + v.w * v.w;
    int sb = s4 * 4;
    tile[ci][sb] = v.x; tile[ci][sb + 1] = v.y; tile[ci][sb + 2] = v.z; tile[ci][sb + 3] = v.w;
  }
#pragma unroll
  for (int m = 1; m < 64; m <<= 1) sq += __shfl_xor(sq, m, 64);
  if ((t & 63) == 0) ssq[t >> 6] = sq;
  __syncthreads();
  if (t == 0) pnorm_part[blockIdx.y * PN_ + p] = ssq[0] + ssq[1] + ssq[2] + ssq[3];
  // 4 kq-groups x 128 s = 512 cells of 16B; 2 cells per thread.
  unsigned short* dp = dst + (size_t)p * HW_ * DIM_ + (size_t)(c0 >> 3) * 1024;
#pragma unroll
  for (int i = 0; i < 2; ++i) {
    int cidx = i * 256 + t;
    int kg = cidx >> 7, s = cidx & 127;
    u16x8 pk;
#pragma unroll
    for (int u = 0; u < 8; ++u) pk[u] = f2bf(tile[kg * 8 + u][s]);
    *(u16x8*)(dp + (size_t)kg * 1024 + (size_t)s * 8) = pk;
  }
}

// ---------------------------------------------------------------------------
// dist partials, T14 async-stage pipeline. 512 blocks, each owns a 512-float
// k-chunk processed in 8 phases of 64.
//
// r6 change: NO ATOMICS. r5 counters showed dist pinned at 54us with every
// pipe idle: 512x256x4 = 524288 device atomicAdds onto dsum's 16 cache lines
// = 32768 serialized ops/line x ~4cyc = ~55us — the entire kernel duration.
// Each block computes 1024 DISTINCT cells (one per thread x 4), so the only
// reduction is across blocks: stage the 1024 partials through LDS scratch
// and write ONE coalesced 4KB plain store to part[b][1024]; select sums.
// ---------------------------------------------------------------------------
__global__ __launch_bounds__(256)
void dist_partial_kernel(const float* __restrict__ x, const float* __restrict__ proto,
                         float* __restrict__ part) {
  __shared__ alignas(16) float xl[2][16][68];
  __shared__ alignas(16) float pl[2][64][68];
  const int t = threadIdx.x, b = blockIdx.x;
  const int n0 = t & 7, pb = t >> 3;          // compute mapping (pb in [0,32))
  const int xr = t >> 4, xc = (t & 15) * 4;   // x-stage mapping
  float acc[2][2] = {};
  const size_t kbase = (size_t)b * 512;

  float4 rx, rp[4];
  auto gload = [&](int ph) {
    const size_t k0 = kbase + ph * 64;
    rx = *(const float4*)(x + (size_t)xr * KFULL + k0 + xc);
#pragma unroll
    for (int i = 0; i < 4; ++i) {
      int idx = i * 256 + t;
      rp[i] = *(const float4*)(proto + (size_t)(idx >> 4) * KFULL + k0 + (idx & 15) * 4);
    }
  };
  auto swrite = [&](int buf) {
    *(float4*)&xl[buf][xr][xc] = rx;
#pragma unroll
    for (int i = 0; i < 4; ++i) {
      int idx = i * 256 + t;
      *(float4*)&pl[buf][idx >> 4][(idx & 15) * 4] = rp[i];
    }
  };

  gload(0); swrite(0);
  __syncthreads();
  for (int ph = 0; ph < 8; ++ph) {
    const int buf = ph & 1;
    if (ph + 1 < 8) gload(ph + 1);   // in flight across compute(ph)
#pragma unroll 8
    for (int k = 0; k < 64; k += 4) {
      float4 xa = *(float4*)&xl[buf][n0][k];
      float4 xb = *(float4*)&xl[buf][n0 + 8][k];
      float4 p0 = *(float4*)&pl[buf][pb][k];
      float4 p1 = *(float4*)&pl[buf][pb + 32][k];
      acc[0][0] += xa.x*p0.x + xa.y*p0.y + xa.z*p0.z + xa.w*p0.w;
      acc[0][1] += xa.x*p1.x + xa.y*p1.y + xa.z*p1.z + xa.w*p1.w;
      acc[1][0] += xb.x*p0.x + xb.y*p0.y + xb.z*p0.z + xb.w*p0.w;
      acc[1][1] += xb.x*p1.x + xb.y*p1.y + xb.z*p1.z + xb.w*p1.w;
    }
    if (ph + 1 < 8) swrite(buf ^ 1);
    __syncthreads();
  }

  // stage partials (cell = n*64+p) in LDS, then one coalesced 4KB store.
  float* scratch = (float*)xl;   // 1024 floats needed; xl holds 2176
  scratch[n0 * 64 + pb]            = -2.f * acc[0][0];
  scratch[n0 * 64 + pb + 32]       = -2.f * acc[0][1];
  scratch[(n0 + 8) * 64 + pb]      = -2.f * acc[1][0];
  scratch[(n0 + 8) * 64 + pb + 32] = -2.f * acc[1][1];
  __syncthreads();
  *(float4*)(part + (size_t)b * 1024 + t * 4) = *(const float4*)&scratch[t * 4];
}

// ---------------------------------------------------------------------------
// select: block n, lane p. Sums the 512 dist partials per cell with 8
// independent accumulator chains (2MB, L2-resident, coalesced 256B/step) and
// the 64 pnorm partials; ranks among 64 (stable argsort order); rank<10 ->
// idx[n][rank]. flags[] pre-zeroed by cvt_all; benign same-value race.
// ---------------------------------------------------------------------------
__global__ __launch_bounds__(64)
void select_kernel(const float* __restrict__ part, const float* __restrict__ pnorm_part,
                   int* __restrict__ idx, int* __restrict__ flags) {
  __shared__ float sh[64];
  const int n = blockIdx.x, t = threadIdx.x;
  float pn = 0.f;
#pragma unroll 8
  for (int cb = 0; cb < DIM_ / 32; ++cb) pn += pnorm_part[cb * PN_ + t];
  const float* pp = part + n * 64 + t;
  float a0 = 0.f, a1 = 0.f, a2 = 0.f, a3 = 0.f, a4 = 0.f, a5 = 0.f, a6 = 0.f, a7 = 0.f;
  for (int b = 0; b < 512; b += 8) {
    a0 += pp[(size_t)(b + 0) * 1024]; a1 += pp[(size_t)(b + 1) * 1024];
    a2 += pp[(size_t)(b + 2) * 1024]; a3 += pp[(size_t)(b + 3) * 1024];
    a4 += pp[(size_t)(b + 4) * 1024]; a5 += pp[(size_t)(b + 5) * 1024];
    a6 += pp[(size_t)(b + 6) * 1024]; a7 += pp[(size_t)(b + 7) * 1024];
  }
  float dval = pn + (((a0 + a1) + (a2 + a3)) + ((a4 + a5) + (a6 + a7)));
  sh[t] = dval;
  __syncthreads();
  int rank = 0;
#pragma unroll
  for (int j = 0; j < 64; ++j) {
    float o = sh[j];
    rank += (o < dval || (o == dval && j < t)) ? 1 : 0;
  }
  if (rank < TOPK_) { idx[n * TOPK_ + rank] = t; flags[t] = 1; }
}

// ---------------------------------------------------------------------------
// bf16 MFMA GEMM, tile 64Mx128Nx64K, 128 threads = 2 waves, wave-tile 64x64
// = 4x4 of 16x16x32. Triple-buffered LDS, 2-deep prefetch, counted vmcnt
// (stage-(it+1) loads stay in flight across the raw s_barrier).
// All staged tensors k-quad-major (W'[kq][O][8], X'[batch][kq][s][8]):
// every global_load_lds reads ONE contiguous 1KB run. Unchanged from r3.
// ---------------------------------------------------------------------------
#define BM 64
#define BKK 64

template <int MODE>
__global__ __launch_bounds__(128, 2)
void mfma_gemm_kernel(const unsigned short* __restrict__ Wb,
                      const unsigned short* __restrict__ Xb,
                      void* __restrict__ OutP,
                      const float* __restrict__ inputs,
                      const int* __restrict__ idxp,
                      const int* __restrict__ flags,
                      int K, int O, int Ldim) {
  __shared__ alignas(16) unsigned short Al[3][8 * BM * 8];    // 3 x 8 KB
  __shared__ alignas(16) unsigned short Bl[3][8 * 128 * 8];   // 3 x 16 KB

  const int t = threadIdx.x;
  const int w = t >> 6;          // wave 0/1 -> n-half
  const int lane = t & 63;
  const int q = lane >> 4;
  const int l15 = lane & 15;
  const int batch = blockIdx.y;
  const int o0 = blockIdx.x * BM;

  if (MODE == 0 && flags && !flags[batch]) return;

  int idreg = 0;
  if (MODE == 1 && lane < TOPK_) idreg = idxp[batch * TOPK_ + lane];

  f32x4 acc[4][4] = {};

  auto issue = [&](int k0, int buf) {
    // A: wave w stages k-quads 4w..4w+3; each load = contiguous 1KB of
    // W'[kq][O][8] starting at output-row o0 (lane*16B appended by HW).
#pragma unroll
    for (int i = 0; i < 4; ++i) {
      int qk = w * 4 + i;
      const unsigned short* ga =
          Wb + (size_t)((k0 >> 3) + qk) * (O * 8) + (size_t)(o0 + lane) * 8;
      __builtin_amdgcn_global_load_lds((const AS1 void*)ga,
                                       (AS3 void*)(&Al[buf][qk * 512]), 16, 0, 0);
    }
    const unsigned short* base;
    if (MODE == 1) {
      int id = __shfl(idreg, k0 >> 8, 64);
      base = Xb + (size_t)id * (HW_ * RF_) + (size_t)((k0 & 255) >> 3) * 1024;
    } else {
      base = Xb + (size_t)batch * HW_ * K + (size_t)(k0 >> 3) * 1024;
    }
    // B: wave w stages 8 of 16 (qk, half) 1KB regions of X'[kq][s][8].
#pragma unroll
    for (int i = 0; i < 8; ++i) {
      int v = w * 8 + i;
      int qk = v >> 1, h = v & 1;
      const unsigned short* gb = base + (size_t)qk * 1024 + (size_t)(h * 64 + lane) * 8;
      __builtin_amdgcn_global_load_lds((const AS1 void*)gb,
                                       (AS3 void*)(&Bl[buf][qk * 1024 + h * 512]), 16, 0, 0);
    }
  };

  const int nIter = K / BKK;   // 32 (MODE 0/2/3) or 40 (MODE 1)

  issue(0, 0);
  issue(BKK, 1);               // 24 loads/wave outstanding

  for (int it = 0; it < nIter; ++it) {
    const int buf = it % 3;
    // Counted wait: stage-it loads (oldest 12) landed; stage-(it+1) loads
    // stay in flight across the barrier. Full drain only on the last iter.
    if (it + 1 < nIter) {
      asm volatile("s_waitcnt vmcnt(12)" ::: "memory");
    } else {
      asm volatile("s_waitcnt vmcnt(0)" ::: "memory");
    }
    __builtin_amdgcn_s_barrier();
#pragma unroll
    for (int s = 0; s < 2; ++s) {
      bf16x8 af[4], bfr[4];
#pragma unroll
      for (int mt = 0; mt < 4; ++mt)
        af[mt] = *(const bf16x8*)(&Al[buf][(s * 4 + q) * 512 + (mt * 16 + l15) * 8]);
#pragma unroll
      for (int nt = 0; nt < 4; ++nt)
        bfr[nt] = *(const bf16x8*)(&Bl[buf][(s * 4 + q) * 1024 + (w * 64 + nt * 16 + l15) * 8]);
#pragma unroll
      for (int mt = 0; mt < 4; ++mt)
#pragma unroll
        for (int nt = 0; nt < 4; ++nt)
          acc[mt][nt] = __builtin_amdgcn_mfma_f32_16x16x32_bf16(af[mt], bfr[nt], acc[mt][nt], 0, 0, 0);
    }
    if (it + 2 < nIter) issue((it + 2) * BKK, (it + 2) % 3);
  }

  // ---------------- epilogue ----------------
  const float CAL = 1.0f - 1.0f / 262144.0f;

  // MODE2 scratch aliases Al buffer 0 (safe: last K-stage uses buffer 1).
  float* nsumS = (float*)&Al[0][0];         // [2][64]
  float* nsqS  = (float*)&Al[0][0] + 128;   // [2][64]

  if (MODE == 2) {
#pragma unroll
    for (int mt = 0; mt < 4; ++mt)
#pragma unroll
      for (int reg = 0; reg < 4; ++reg) {
        float s_ = 0.f, q_ = 0.f;
#pragma unroll
        for (int nt = 0; nt < 4; ++nt) {
          float v = acc[mt][nt][reg];
          s_ += v; q_ += v * v;
        }
#pragma unroll
        for (int m = 1; m < 16; m <<= 1) {
          s_ += __shfl_xor(s_, m, 64);
          q_ += __shfl_xor(q_, m, 64);
        }
        if (l15 == 0) {
          int ol = mt * 16 + q * 4 + reg;
          nsumS[w * 64 + ol] = s_; nsqS[w * 64 + ol] = q_;
        }
      }
    __syncthreads();
  }

  if (MODE == 3) {
    float* ofb = (float*)OutP + (size_t)batch * DIM_ * HW_;
    const float* inb = inputs + (size_t)batch * DIM_ * HW_;
#pragma unroll
    for (int mt = 0; mt < 4; ++mt)
#pragma unroll
      for (int nt = 0; nt < 4; ++nt) {
        int o = o0 + mt * 16 + q * 4;
        int s = w * 64 + nt * 16 + l15;
        f32x4 v = acc[mt][nt];
#pragma unroll
        for (int g = 0; g < 4; ++g) {
          float in = inb[(size_t)(o + g) * HW_ + s];
          float sg = 1.f / (1.f + expf(-v[g]));
          ofb[(size_t)(o + g) * HW_ + s] = in * (1.f + sg);
        }
      }
  } else {
    // Store to X'[batch][o/8][s][8] (k-quad-major): ushort4 at
    // (o>>3)*1024 + s*8 + (o&7); (o&7) in {0,4}. Contiguous 256B per
    // 16-lane group instead of a 64-line scatter.
    unsigned short* ob = (unsigned short*)OutP + (size_t)batch * HW_ * Ldim;
    const float* inb = (MODE == 1) ? inputs + (size_t)batch * DIM_ * HW_ : nullptr;
#pragma unroll
    for (int mt = 0; mt < 4; ++mt) {
      float mean[4], rs[4];
      if (MODE == 2) {
#pragma unroll
        for (int reg = 0; reg < 4; ++reg) {
          int ol = mt * 16 + q * 4 + reg;
          float ts = nsumS[ol] + nsumS[64 + ol];
          float tq = nsqS[ol] + nsqS[64 + ol];
          float mn = ts * (1.f / 128.f);
          float vr = tq * (1.f / 128.f) - mn * mn;
          mean[reg] = mn; rs[reg] = rsqrtf(vr + 1e-5f);
        }
      }
#pragma unroll
      for (int nt = 0; nt < 4; ++nt) {
        int o = o0 + mt * 16 + q * 4;
        int s = w * 64 + nt * 16 + l15;
        f32x4 v = acc[mt][nt];
        float r[4];
        if (MODE == 0) {
#pragma unroll
          for (int g = 0; g < 4; ++g) r[g] = v[g];
        } else if (MODE == 1) {
          const float* ip = inb + (size_t)o * HW_ + s;
#pragma unroll
          for (int g = 0; g < 4; ++g)
            r[g] = fmaxf(0.f, 0.5f * ip[(size_t)g * HW_] + CAL * v[g]);
        } else {
#pragma unroll
          for (int g = 0; g < 4; ++g) r[g] = (v[g] - mean[g]) * rs[g];
        }
        ushort4 pk;
        pk.x = f2bf(r[0]); pk.y = f2bf(r[1]); pk.z = f2bf(r[2]); pk.w = f2bf(r[3]);
        *(ushort4*)(ob + (size_t)(o >> 3) * 1024 + (size_t)s * 8 + (o & 7)) = pk;
      }
    }
  }
}

// ---------------------------------------------------------------------------
extern "C" void kernel_launch(void* const* d_in, const int* in_sizes, int n_in,
                              void* d_out, int out_size, void* d_ws, size_t ws_size,
                              hipStream_t stream) {
  const float* inputs = (const float*)d_in[0];
  const float* proto  = (const float*)d_in[1];
  const float* w_rf   = (const float*)d_in[2];
  const float* w_rfmv = (const float*)d_in[3];
  const float* w_rms  = (const float*)d_in[4];
  const float* w_fuse = (const float*)d_in[5];
  float* out = (float*)d_out;

  uint8_t* ws = (uint8_t*)d_ws;
  size_t off = 0;
  auto alloc = [&](size_t bytes) { uint8_t* p = ws + off; off += (bytes + 255) & ~(size_t)255; return p; };

  float* dsum  = (float*)alloc(1088 * 4);       // 4352 B (256-aligned size)
  int*   flags = (int*)alloc(PN_ * 4);          // contiguous after dsum -> zeroed together
  int*   idx   = (int*)alloc(N_ * TOPK_ * 4);
  float* pnorm = (float*)alloc((size_t)(DIM_ / 32) * PN_ * 4);   // 64x64 partials
  float* part  = (float*)alloc((size_t)512 * 1024 * 4);          // 2MB dist partials
  unsigned short* wrf_b   = (unsigned short*)alloc((size_t)RF_ * DIM_ * 2);
  unsigned short* wrfmv_b = (unsigned short*)alloc((size_t)DIM_ * KMV * 2);
  unsigned short* wrms_b  = (unsigned short*)alloc((size_t)DIM_ * DIM_ * 2);
  unsigned short* wfuse_b = (unsigned short*)alloc((size_t)DIM_ * DIM_ * 2);
  unsigned short* xpT     = (unsigned short*)alloc((size_t)PN_ * HW_ * RF_ * 2);
  unsigned short* protoT  = (unsigned short*)alloc((size_t)PN_ * HW_ * DIM_ * 2);
  unsigned short* mvlT = protoT;                 // aliases (protoT dead after G1)
  unsigned short* mvaT = protoT + (size_t)N_ * HW_ * DIM_;

  cvt_all_kernel<<<864, 256, 0, stream>>>(w_rf, w_rfmv, w_rms, w_fuse,
                                          wrf_b, wrfmv_b, wrms_b, wfuse_b, dsum);
  transpose_proto_kernel<<<dim3(PN_, DIM_ / 32), 256, 0, stream>>>(proto, protoT, pnorm);
  dist_partial_kernel<<<512, 256, 0, stream>>>(inputs, proto, part);
  select_kernel<<<N_, 64, 0, stream>>>(part, pnorm, idx, flags);

  mfma_gemm_kernel<0><<<dim3(RF_ / BM, PN_), 128, 0, stream>>>(
      wrf_b, protoT, xpT, nullptr, nullptr, flags, DIM_, RF_, RF_);
  mfma_gemm_kernel<1><<<dim3(DIM_ / BM, N_), 128, 0, stream>>>(
      wrfmv_b, xpT, mvlT, inputs, idx, nullptr, KMV, DIM_, DIM_);
  mfma_gemm_kernel<2><<<dim3(DIM_ / BM, N_), 128, 0, stream>>>(
      wrms_b, mvlT, mvaT, nullptr, nullptr, nullptr, DIM_, DIM_, DIM_);
  mfma_gemm_kernel<3><<<dim3(DIM_ / BM, N_), 128, 0, stream>>>(
      wfuse_b, mvaT, out, inputs, nullptr, nullptr, DIM_, DIM_, DIM_);
}

// Round 7
// 316.430 us; speedup vs baseline: 1.2136x; 1.2136x over previous
//
#include <hip/hip_runtime.h>
#include <cstdint>
#include <cstddef>

#define N_    16
#define DIM_  2048
#define RF_   256
#define PN_   64
#define TOPK_ 10
#define HW_   128
#define KFULL (DIM_*HW_)   /* 262144 */
#define KMV   (TOPK_*RF_)  /* 2560 */

#define AS1 __attribute__((address_space(1)))
#define AS3 __attribute__((address_space(3)))

typedef __attribute__((ext_vector_type(8))) short bf16x8;
typedef __attribute__((ext_vector_type(4))) float f32x4;
typedef __attribute__((ext_vector_type(8))) unsigned short u16x8;

__device__ __forceinline__ unsigned short f2bf(float f) {
  unsigned u = __builtin_bit_cast(unsigned, f);
  unsigned r = (u + 0x7FFFu + ((u >> 16) & 1u)) >> 16;
  return (unsigned short)r;
}

// ---------------------------------------------------------------------------
// Weight convert fp32 [O][C] -> bf16 k-quad-major W'[C/8][O][8], LDS-tiled so
// BOTH sides are coalesced. Tile = 64 o x 32 cg cells (16B/cell).
// Also zero-inits dsum+flags. Grid: 864 tiles (32 + 320 + 256 + 256).
// ---------------------------------------------------------------------------
__global__ __launch_bounds__(256)
void cvt_all_kernel(const float* __restrict__ s0, const float* __restrict__ s1,
                    const float* __restrict__ s2, const float* __restrict__ s3,
                    unsigned short* __restrict__ d0, unsigned short* __restrict__ d1,
                    unsigned short* __restrict__ d2, unsigned short* __restrict__ d3,
                    float* __restrict__ dsum) {
  __shared__ u16x8 tile[32][65];   // [cg_local][o_local], +1 cell pad
  const int t = threadIdx.x;
  int gid = blockIdx.x * 256 + t;
  if (gid < 1152) dsum[gid] = 0.f;   // dsum (1088) + flags (64), contiguous

  int bid = blockIdx.x;
  const float* s; unsigned short* d; int O, CG, tb;
  if (bid < 32)       { s = s0; d = d0; O = RF_;  CG = DIM_ / 8; tb = bid; }
  else if (bid < 352) { s = s1; d = d1; O = DIM_; CG = KMV  / 8; tb = bid - 32; }
  else if (bid < 608) { s = s2; d = d2; O = DIM_; CG = DIM_ / 8; tb = bid - 352; }
  else                { s = s3; d = d3; O = DIM_; CG = DIM_ / 8; tb = bid - 608; }
  const int nCgT = CG / 32;
  const int o0  = (tb / nCgT) * 64;
  const int cg0 = (tb % nCgT) * 32;
  const size_t C = (size_t)CG * 8;

  // read + convert: idx = i*256+t -> o_l = idx>>5, cg_l = idx&31
#pragma unroll
  for (int i = 0; i < 8; ++i) {
    int idx = i * 256 + t, ol = idx >> 5, cg = idx & 31;
    const float* sp = s + (size_t)(o0 + ol) * C + (size_t)(cg0 + cg) * 8;
    float4 a = *(const float4*)sp;
    float4 b = *(const float4*)(sp + 4);
    u16x8 pk;
    pk[0] = f2bf(a.x); pk[1] = f2bf(a.y); pk[2] = f2bf(a.z); pk[3] = f2bf(a.w);
    pk[4] = f2bf(b.x); pk[5] = f2bf(b.y); pk[6] = f2bf(b.z); pk[7] = f2bf(b.w);
    tile[cg][ol] = pk;
  }
  __syncthreads();
  // write: idx -> cg_l = idx>>6, o_l = idx&63
#pragma unroll
  for (int i = 0; i < 8; ++i) {
    int idx = i * 256 + t, cg = idx >> 6, ol = idx & 63;
    *(u16x8*)(d + (size_t)(cg0 + cg) * ((size_t)O * 8) + (size_t)(o0 + ol) * 8) =
        tile[cg][ol];
  }
}

// ---------------------------------------------------------------------------
// proto [64][2048][128] fp32 -> protoT' [64][kq=256][s=128][8] bf16
// (k-quad-major). ||p||^2 partial: block-reduce then ONE PLAIN STORE per
// block into pnorm_part[cb][p]; select_kernel sums the 64 partials.
// ---------------------------------------------------------------------------
__global__ __launch_bounds__(256)
void transpose_proto_kernel(const float* __restrict__ src,
                            unsigned short* __restrict__ dst,
                            float* __restrict__ pnorm_part) {
  __shared__ float tile[32][129];
  __shared__ float ssq[4];
  const int p = blockIdx.x;
  const int c0 = blockIdx.y * 32;
  const int t = threadIdx.x;
  const float* sp = src + ((size_t)p * DIM_ + c0) * HW_;
  float sq = 0.f;
#pragma unroll
  for (int i = 0; i < 4; ++i) {
    int g = i * 256 + t;
    int ci = g >> 5, s4 = g & 31;
    float4 v = *(const float4*)(sp + (size_t)ci * HW_ + s4 * 4);
    sq += v.x * v.x + v.y * v.y + v.z * v.z + v.w * v.w;
    int sb = s4 * 4;
    tile[ci][sb] = v.x; tile[ci][sb + 1] = v.y; tile[ci][sb + 2] = v.z; tile[ci][sb + 3] = v.w;
  }
#pragma unroll
  for (int m = 1; m < 64; m <<= 1) sq += __shfl_xor(sq, m, 64);
  if ((t & 63) == 0) ssq[t >> 6] = sq;
  __syncthreads();
  if (t == 0) pnorm_part[blockIdx.y * PN_ + p] = ssq[0] + ssq[1] + ssq[2] + ssq[3];
  // 4 kq-groups x 128 s = 512 cells of 16B; 2 cells per thread.
  unsigned short* dp = dst + (size_t)p * HW_ * DIM_ + (size_t)(c0 >> 3) * 1024;
#pragma unroll
  for (int i = 0; i < 2; ++i) {
    int cidx = i * 256 + t;
    int kg = cidx >> 7, s = cidx & 127;
    u16x8 pk;
#pragma unroll
    for (int u = 0; u < 8; ++u) pk[u] = f2bf(tile[kg * 8 + u][s]);
    *(u16x8*)(dp + (size_t)kg * 1024 + (size_t)s * 8) = pk;
  }
}

// ---------------------------------------------------------------------------
// dist partials, T14 async-stage pipeline, NO atomics: each block stages its
// 1024 distinct cells through LDS and writes one coalesced 4KB plain store
// to part[b][1024]; select sums across blocks.
// ---------------------------------------------------------------------------
__global__ __launch_bounds__(256)
void dist_partial_kernel(const float* __restrict__ x, const float* __restrict__ proto,
                         float* __restrict__ part) {
  __shared__ alignas(16) float xl[2][16][68];
  __shared__ alignas(16) float pl[2][64][68];
  const int t = threadIdx.x, b = blockIdx.x;
  const int n0 = t & 7, pb = t >> 3;          // compute mapping (pb in [0,32))
  const int xr = t >> 4, xc = (t & 15) * 4;   // x-stage mapping
  float acc[2][2] = {};
  const size_t kbase = (size_t)b * 512;

  float4 rx, rp[4];
  auto gload = [&](int ph) {
    const size_t k0 = kbase + ph * 64;
    rx = *(const float4*)(x + (size_t)xr * KFULL + k0 + xc);
#pragma unroll
    for (int i = 0; i < 4; ++i) {
      int idx = i * 256 + t;
      rp[i] = *(const float4*)(proto + (size_t)(idx >> 4) * KFULL + k0 + (idx & 15) * 4);
    }
  };
  auto swrite = [&](int buf) {
    *(float4*)&xl[buf][xr][xc] = rx;
#pragma unroll
    for (int i = 0; i < 4; ++i) {
      int idx = i * 256 + t;
      *(float4*)&pl[buf][idx >> 4][(idx & 15) * 4] = rp[i];
    }
  };

  gload(0); swrite(0);
  __syncthreads();
  for (int ph = 0; ph < 8; ++ph) {
    const int buf = ph & 1;
    if (ph + 1 < 8) gload(ph + 1);   // in flight across compute(ph)
#pragma unroll 8
    for (int k = 0; k < 64; k += 4) {
      float4 xa = *(float4*)&xl[buf][n0][k];
      float4 xb = *(float4*)&xl[buf][n0 + 8][k];
      float4 p0 = *(float4*)&pl[buf][pb][k];
      float4 p1 = *(float4*)&pl[buf][pb + 32][k];
      acc[0][0] += xa.x*p0.x + xa.y*p0.y + xa.z*p0.z + xa.w*p0.w;
      acc[0][1] += xa.x*p1.x + xa.y*p1.y + xa.z*p1.z + xa.w*p1.w;
      acc[1][0] += xb.x*p0.x + xb.y*p0.y + xb.z*p0.z + xb.w*p0.w;
      acc[1][1] += xb.x*p1.x + xb.y*p1.y + xb.z*p1.z + xb.w*p1.w;
    }
    if (ph + 1 < 8) swrite(buf ^ 1);
    __syncthreads();
  }

  float* scratch = (float*)xl;   // 1024 floats needed; xl holds 2176
  scratch[n0 * 64 + pb]            = -2.f * acc[0][0];
  scratch[n0 * 64 + pb + 32]       = -2.f * acc[0][1];
  scratch[(n0 + 8) * 64 + pb]      = -2.f * acc[1][0];
  scratch[(n0 + 8) * 64 + pb + 32] = -2.f * acc[1][1];
  __syncthreads();
  *(float4*)(part + (size_t)b * 1024 + t * 4) = *(const float4*)&scratch[t * 4];
}

// ---------------------------------------------------------------------------
// select (r7: 512 threads). r6's 64-lane version serialized 512 strided L2
// reads per lane (~10us, latency-bound at 1024 threads chip-wide). Now 8
// chunk-groups of 64 lanes each sum 64 partial-blocks (4 indep chains), LDS
// combine, then the first 64 lanes rank as before.
// ---------------------------------------------------------------------------
__global__ __launch_bounds__(512)
void select_kernel(const float* __restrict__ part, const float* __restrict__ pnorm_part,
                   int* __restrict__ idx, int* __restrict__ flags) {
  __shared__ float red[8][64];
  __shared__ float sh[64];
  const int n = blockIdx.x, t = threadIdx.x;
  const int c = t & 63, ch = t >> 6;
  const float* pp = part + (size_t)ch * 64 * 1024 + n * 64 + c;
  float a0 = 0.f, a1 = 0.f, a2 = 0.f, a3 = 0.f;
  for (int b = 0; b < 64; b += 4) {
    a0 += pp[(size_t)(b + 0) * 1024];
    a1 += pp[(size_t)(b + 1) * 1024];
    a2 += pp[(size_t)(b + 2) * 1024];
    a3 += pp[(size_t)(b + 3) * 1024];
  }
  red[ch][c] = (a0 + a1) + (a2 + a3);
  __syncthreads();
  if (t < 64) {
    float pn = 0.f;
#pragma unroll 8
    for (int cb = 0; cb < DIM_ / 32; ++cb) pn += pnorm_part[cb * PN_ + t];
    float dv = pn;
#pragma unroll
    for (int i = 0; i < 8; ++i) dv += red[i][t];
    sh[t] = dv;
  }
  __syncthreads();
  if (t < 64) {
    float dval = sh[t];
    int rank = 0;
#pragma unroll
    for (int j = 0; j < 64; ++j) {
      float o = sh[j];
      rank += (o < dval || (o == dval && j < t)) ? 1 : 0;
    }
    if (rank < TOPK_) { idx[n * TOPK_ + rank] = t; flags[t] = 1; }
  }
}

// ---------------------------------------------------------------------------
// bf16 MFMA GEMM, tile 64Mx128Nx64K. r7 change: 256 threads = 4 WAVES (was
// 2). r6 counters: dur 43.5us vs ~7us compute floor, MfmaUtil 14-18%,
// VALUBusy 15-18%, HBM <18%, Occupancy 9% -> latency-bound at 1 wave/SIMD;
// LDS (72KB, 2 blocks/CU) blocks more blocks, so double waves/block instead:
// wave w owns a 32x64 quadrant (m-half = w>>1, n-half = w&1), acc 2x4,
// staging 6 loads/wave (A 2 + B 4), depth-2 prefetch -> counted vmcnt(6).
// Same tile, same traffic, same 3-buffer pipeline, 2x TLP (8 waves/CU).
//
// All staged tensors k-quad-major (W'[kq][O][8], X'[batch][kq][s][8]):
// every global_load_lds reads ONE contiguous 1KB run.
// LDS: A cell(qk,m)=16B @ qk*1024B + m*16B; B cell(qk,n)=qk*2048B + n*16B.
// ---------------------------------------------------------------------------
#define BM 64
#define BKK 64

template <int MODE>
__global__ __launch_bounds__(256, 2)
void mfma_gemm_kernel(const unsigned short* __restrict__ Wb,
                      const unsigned short* __restrict__ Xb,
                      void* __restrict__ OutP,
                      const float* __restrict__ inputs,
                      const int* __restrict__ idxp,
                      const int* __restrict__ flags,
                      int K, int O, int Ldim) {
  __shared__ alignas(16) unsigned short Al[3][8 * BM * 8];    // 3 x 8 KB
  __shared__ alignas(16) unsigned short Bl[3][8 * 128 * 8];   // 3 x 16 KB

  const int t = threadIdx.x;
  const int w = t >> 6;          // wave 0..3
  const int lane = t & 63;
  const int q = lane >> 4;
  const int l15 = lane & 15;
  const int m2 = w >> 1;         // m-half (32 rows)
  const int h  = w & 1;          // n-half (64 cols)
  const int batch = blockIdx.y;
  const int o0 = blockIdx.x * BM;

  if (MODE == 0 && flags && !flags[batch]) return;

  int idreg = 0;
  if (MODE == 1 && lane < TOPK_) idreg = idxp[batch * TOPK_ + lane];

  f32x4 acc[2][4] = {};

  auto issue = [&](int k0, int buf) {
    // A: wave w stages k-quads 2w, 2w+1 (contiguous 1KB each of W'[kq][O][8])
#pragma unroll
    for (int i = 0; i < 2; ++i) {
      int qk = w * 2 + i;
      const unsigned short* ga =
          Wb + (size_t)((k0 >> 3) + qk) * (O * 8) + (size_t)(o0 + lane) * 8;
      __builtin_amdgcn_global_load_lds((const AS1 void*)ga,
                                       (AS3 void*)(&Al[buf][qk * 512]), 16, 0, 0);
    }
    const unsigned short* base;
    if (MODE == 1) {
      int id = __shfl(idreg, k0 >> 8, 64);
      base = Xb + (size_t)id * (HW_ * RF_) + (size_t)((k0 & 255) >> 3) * 1024;
    } else {
      base = Xb + (size_t)batch * HW_ * K + (size_t)(k0 >> 3) * 1024;
    }
    // B: wave w stages 4 of 16 (qk, half) 1KB regions of X'[kq][s][8].
#pragma unroll
    for (int i = 0; i < 4; ++i) {
      int v = w * 4 + i;
      int qk = v >> 1, hh = v & 1;
      const unsigned short* gb = base + (size_t)qk * 1024 + (size_t)(hh * 64 + lane) * 8;
      __builtin_amdgcn_global_load_lds((const AS1 void*)gb,
                                       (AS3 void*)(&Bl[buf][qk * 1024 + hh * 512]), 16, 0, 0);
    }
  };

  const int nIter = K / BKK;   // 32 (MODE 0/2/3) or 40 (MODE 1)

  issue(0, 0);
  issue(BKK, 1);               // 12 loads/wave outstanding

  for (int it = 0; it < nIter; ++it) {
    const int buf = it % 3;
    // Counted wait: stage-it loads (oldest 6) landed; stage-(it+1) loads
    // stay in flight across the barrier. Full drain only on the last iter.
    if (it + 1 < nIter) {
      asm volatile("s_waitcnt vmcnt(6)" ::: "memory");
    } else {
      asm volatile("s_waitcnt vmcnt(0)" ::: "memory");
    }
    __builtin_amdgcn_s_barrier();
#pragma unroll
    for (int s = 0; s < 2; ++s) {
      bf16x8 af[2], bfr[4];
#pragma unroll
      for (int mt = 0; mt < 2; ++mt)
        af[mt] = *(const bf16x8*)(&Al[buf][(s * 4 + q) * 512 + (m2 * 32 + mt * 16 + l15) * 8]);
#pragma unroll
      for (int nt = 0; nt < 4; ++nt)
        bfr[nt] = *(const bf16x8*)(&Bl[buf][(s * 4 + q) * 1024 + (h * 64 + nt * 16 + l15) * 8]);
#pragma unroll
      for (int mt = 0; mt < 2; ++mt)
#pragma unroll
        for (int nt = 0; nt < 4; ++nt)
          acc[mt][nt] = __builtin_amdgcn_mfma_f32_16x16x32_bf16(af[mt], bfr[nt], acc[mt][nt], 0, 0, 0);
    }
    if (it + 2 < nIter) issue((it + 2) * BKK, (it + 2) % 3);
  }

  // ---------------- epilogue ----------------
  const float CAL = 1.0f - 1.0f / 262144.0f;

  // MODE2 scratch aliases Al buffer 0 (safe: last K-stage uses buffer 1,
  // and the barrier at the top of the final iter retired all buffer-0 reads).
  float* nsumS = (float*)&Al[0][0];         // [4][32]
  float* nsqS  = (float*)&Al[0][0] + 128;   // [4][32]

  if (MODE == 2) {
#pragma unroll
    for (int mt = 0; mt < 2; ++mt)
#pragma unroll
      for (int reg = 0; reg < 4; ++reg) {
        float s_ = 0.f, q_ = 0.f;
#pragma unroll
        for (int nt = 0; nt < 4; ++nt) {
          float v = acc[mt][nt][reg];
          s_ += v; q_ += v * v;
        }
#pragma unroll
        for (int m = 1; m < 16; m <<= 1) {
          s_ += __shfl_xor(s_, m, 64);
          q_ += __shfl_xor(q_, m, 64);
        }
        if (l15 == 0) {
          int ol = mt * 16 + q * 4 + reg;     // [0,32) within wave's m-half
          nsumS[w * 32 + ol] = s_; nsqS[w * 32 + ol] = q_;
        }
      }
    __syncthreads();
  }

  if (MODE == 3) {
    float* ofb = (float*)OutP + (size_t)batch * DIM_ * HW_;
    const float* inb = inputs + (size_t)batch * DIM_ * HW_;
#pragma unroll
    for (int mt = 0; mt < 2; ++mt)
#pragma unroll
      for (int nt = 0; nt < 4; ++nt) {
        int o = o0 + m2 * 32 + mt * 16 + q * 4;
        int s = h * 64 + nt * 16 + l15;
        f32x4 v = acc[mt][nt];
#pragma unroll
        for (int g = 0; g < 4; ++g) {
          float in = inb[(size_t)(o + g) * HW_ + s];
          float sg = 1.f / (1.f + expf(-v[g]));
          ofb[(size_t)(o + g) * HW_ + s] = in * (1.f + sg);
        }
      }
  } else {
    // Store to X'[batch][o/8][s][8] (k-quad-major): ushort4 at
    // (o>>3)*1024 + s*8 + (o&7); contiguous 256B per 16-lane group.
    unsigned short* ob = (unsigned short*)OutP + (size_t)batch * HW_ * Ldim;
    const float* inb = (MODE == 1) ? inputs + (size_t)batch * DIM_ * HW_ : nullptr;
#pragma unroll
    for (int mt = 0; mt < 2; ++mt) {
      float mean[4], rs[4];
      if (MODE == 2) {
#pragma unroll
        for (int reg = 0; reg < 4; ++reg) {
          int ol = mt * 16 + q * 4 + reg;
          // combine the two n-half waves of this m-half (w = m2*2 + h)
          float ts = nsumS[(m2 * 2 + 0) * 32 + ol] + nsumS[(m2 * 2 + 1) * 32 + ol];
          float tq = nsqS[(m2 * 2 + 0) * 32 + ol] + nsqS[(m2 * 2 + 1) * 32 + ol];
          float mn = ts * (1.f / 128.f);
          float vr = tq * (1.f / 128.f) - mn * mn;
          mean[reg] = mn; rs[reg] = rsqrtf(vr + 1e-5f);
        }
      }
#pragma unroll
      for (int nt = 0; nt < 4; ++nt) {
        int o = o0 + m2 * 32 + mt * 16 + q * 4;
        int s = h * 64 + nt * 16 + l15;
        f32x4 v = acc[mt][nt];
        float r[4];
        if (MODE == 0) {
#pragma unroll
          for (int g = 0; g < 4; ++g) r[g] = v[g];
        } else if (MODE == 1) {
          const float* ip = inb + (size_t)o * HW_ + s;
#pragma unroll
          for (int g = 0; g < 4; ++g)
            r[g] = fmaxf(0.f, 0.5f * ip[(size_t)g * HW_] + CAL * v[g]);
        } else {
#pragma unroll
          for (int g = 0; g < 4; ++g) r[g] = (v[g] - mean[g]) * rs[g];
        }
        ushort4 pk;
        pk.x = f2bf(r[0]); pk.y = f2bf(r[1]); pk.z = f2bf(r[2]); pk.w = f2bf(r[3]);
        *(ushort4*)(ob + (size_t)(o >> 3) * 1024 + (size_t)s * 8 + (o & 7)) = pk;
      }
    }
  }
}

// ---------------------------------------------------------------------------
extern "C" void kernel_launch(void* const* d_in, const int* in_sizes, int n_in,
                              void* d_out, int out_size, void* d_ws, size_t ws_size,
                              hipStream_t stream) {
  const float* inputs = (const float*)d_in[0];
  const float* proto  = (const float*)d_in[1];
  const float* w_rf   = (const float*)d_in[2];
  const float* w_rfmv = (const float*)d_in[3];
  const float* w_rms  = (const float*)d_in[4];
  const float* w_fuse = (const float*)d_in[5];
  float* out = (float*)d_out;

  uint8_t* ws = (uint8_t*)d_ws;
  size_t off = 0;
  auto alloc = [&](size_t bytes) { uint8_t* p = ws + off; off += (bytes + 255) & ~(size_t)255; return p; };

  float* dsum  = (float*)alloc(1088 * 4);       // 4352 B (256-aligned size)
  int*   flags = (int*)alloc(PN_ * 4);          // contiguous after dsum -> zeroed together
  int*   idx   = (int*)alloc(N_ * TOPK_ * 4);
  float* pnorm = (float*)alloc((size_t)(DIM_ / 32) * PN_ * 4);   // 64x64 partials
  float* part  = (float*)alloc((size_t)512 * 1024 * 4);          // 2MB dist partials
  unsigned short* wrf_b   = (unsigned short*)alloc((size_t)RF_ * DIM_ * 2);
  unsigned short* wrfmv_b = (unsigned short*)alloc((size_t)DIM_ * KMV * 2);
  unsigned short* wrms_b  = (unsigned short*)alloc((size_t)DIM_ * DIM_ * 2);
  unsigned short* wfuse_b = (unsigned short*)alloc((size_t)DIM_ * DIM_ * 2);
  unsigned short* xpT     = (unsigned short*)alloc((size_t)PN_ * HW_ * RF_ * 2);
  unsigned short* protoT  = (unsigned short*)alloc((size_t)PN_ * HW_ * DIM_ * 2);
  unsigned short* mvlT = protoT;                 // aliases (protoT dead after G1)
  unsigned short* mvaT = protoT + (size_t)N_ * HW_ * DIM_;

  cvt_all_kernel<<<864, 256, 0, stream>>>(w_rf, w_rfmv, w_rms, w_fuse,
                                          wrf_b, wrfmv_b, wrms_b, wfuse_b, dsum);
  transpose_proto_kernel<<<dim3(PN_, DIM_ / 32), 256, 0, stream>>>(proto, protoT, pnorm);
  dist_partial_kernel<<<512, 256, 0, stream>>>(inputs, proto, part);
  select_kernel<<<N_, 512, 0, stream>>>(part, pnorm, idx, flags);

  mfma_gemm_kernel<0><<<dim3(RF_ / BM, PN_), 256, 0, stream>>>(
      wrf_b, protoT, xpT, nullptr, nullptr, flags, DIM_, RF_, RF_);
  mfma_gemm_kernel<1><<<dim3(DIM_ / BM, N_), 256, 0, stream>>>(
      wrfmv_b, xpT, mvlT, inputs, idx, nullptr, KMV, DIM_, DIM_);
  mfma_gemm_kernel<2><<<dim3(DIM_ / BM, N_), 256, 0, stream>>>(
      wrms_b, mvlT, mvaT, nullptr, nullptr, nullptr, DIM_, DIM_, DIM_);
  mfma_gemm_kernel<3><<<dim3(DIM_ / BM, N_), 256, 0, stream>>>(
      wfuse_b, mvaT, out, inputs, nullptr, nullptr, DIM_, DIM_, DIM_);
}

// Round 8
// 302.954 us; speedup vs baseline: 1.2675x; 1.0445x over previous
//
#include <hip/hip_runtime.h>
#include <cstdint>
#include <cstddef>

#define N_    16
#define DIM_  2048
#define RF_   256
#define PN_   64
#define TOPK_ 10
#define HW_   128
#define KFULL (DIM_*HW_)   /* 262144 */
#define KMV   (TOPK_*RF_)  /* 2560 */

#define AS1 __attribute__((address_space(1)))
#define AS3 __attribute__((address_space(3)))

typedef __attribute__((ext_vector_type(8))) short bf16x8;
typedef __attribute__((ext_vector_type(4))) float f32x4;
typedef __attribute__((ext_vector_type(8))) unsigned short u16x8;

__device__ __forceinline__ unsigned short f2bf(float f) {
  unsigned u = __builtin_bit_cast(unsigned, f);
  unsigned r = (u + 0x7FFFu + ((u >> 16) & 1u)) >> 16;
  return (unsigned short)r;
}

// ---------------------------------------------------------------------------
// FRONT kernel (r8): fuses the three independent preprocessing kernels
// (dist_partial / transpose_proto / cvt_all) into ONE dispatch so their
// memory streams overlap instead of serializing (each underfills the chip
// alone; combined traffic ~200MB ~= 32us at achievable BW vs ~60us serial).
// Role by block range: [0,512) dist, [512,4608) transpose, [4608,5472) cvt.
// One 43520-B LDS union (= dist's requirement) -> 3 blocks/CU all roles.
// Bodies are verbatim from r7; only block-index mapping changed.
// ---------------------------------------------------------------------------
__global__ __launch_bounds__(256)
void front_kernel(const float* __restrict__ x, const float* __restrict__ proto,
                  float* __restrict__ part,
                  unsigned short* __restrict__ protoT, float* __restrict__ pnorm_part,
                  const float* __restrict__ s0, const float* __restrict__ s1,
                  const float* __restrict__ s2, const float* __restrict__ s3,
                  unsigned short* __restrict__ d0, unsigned short* __restrict__ d1,
                  unsigned short* __restrict__ d2, unsigned short* __restrict__ d3,
                  float* __restrict__ dsum) {
  __shared__ alignas(16) unsigned char ldsbuf[43520];
  const int t = threadIdx.x;
  const int bid = blockIdx.x;
  {
    int g = bid * 256 + t;
    if (g < 1152) dsum[g] = 0.f;   // dsum (1088) + flags (64), contiguous
  }

  if (bid < 512) {
    // ---------------- dist role (T14 pipeline, no atomics) ----------------
    float (*xl)[16][68] = (float (*)[16][68])ldsbuf;            // 8704 B
    float (*pl)[64][68] = (float (*)[64][68])(ldsbuf + 8704);   // 34816 B
    const int b = bid;
    const int n0 = t & 7, pb = t >> 3;
    const int xr = t >> 4, xc = (t & 15) * 4;
    float acc[2][2] = {};
    const size_t kbase = (size_t)b * 512;

    float4 rx, rp[4];
    auto gload = [&](int ph) {
      const size_t k0 = kbase + ph * 64;
      rx = *(const float4*)(x + (size_t)xr * KFULL + k0 + xc);
#pragma unroll
      for (int i = 0; i < 4; ++i) {
        int idx = i * 256 + t;
        rp[i] = *(const float4*)(proto + (size_t)(idx >> 4) * KFULL + k0 + (idx & 15) * 4);
      }
    };
    auto swrite = [&](int buf) {
      *(float4*)&xl[buf][xr][xc] = rx;
#pragma unroll
      for (int i = 0; i < 4; ++i) {
        int idx = i * 256 + t;
        *(float4*)&pl[buf][idx >> 4][(idx & 15) * 4] = rp[i];
      }
    };

    gload(0); swrite(0);
    __syncthreads();
    for (int ph = 0; ph < 8; ++ph) {
      const int buf = ph & 1;
      if (ph + 1 < 8) gload(ph + 1);
#pragma unroll 8
      for (int k = 0; k < 64; k += 4) {
        float4 xa = *(float4*)&xl[buf][n0][k];
        float4 xb = *(float4*)&xl[buf][n0 + 8][k];
        float4 p0 = *(float4*)&pl[buf][pb][k];
        float4 p1 = *(float4*)&pl[buf][pb + 32][k];
        acc[0][0] += xa.x*p0.x + xa.y*p0.y + xa.z*p0.z + xa.w*p0.w;
        acc[0][1] += xa.x*p1.x + xa.y*p1.y + xa.z*p1.z + xa.w*p1.w;
        acc[1][0] += xb.x*p0.x + xb.y*p0.y + xb.z*p0.z + xb.w*p0.w;
        acc[1][1] += xb.x*p1.x + xb.y*p1.y + xb.z*p1.z + xb.w*p1.w;
      }
      if (ph + 1 < 8) swrite(buf ^ 1);
      __syncthreads();
    }

    float* scratch = (float*)ldsbuf;
    scratch[n0 * 64 + pb]            = -2.f * acc[0][0];
    scratch[n0 * 64 + pb + 32]       = -2.f * acc[0][1];
    scratch[(n0 + 8) * 64 + pb]      = -2.f * acc[1][0];
    scratch[(n0 + 8) * 64 + pb + 32] = -2.f * acc[1][1];
    __syncthreads();
    *(float4*)(part + (size_t)b * 1024 + t * 4) = *(const float4*)&scratch[t * 4];

  } else if (bid < 4608) {
    // ---------------- transpose role ----------------
    float (*tile)[129] = (float (*)[129])ldsbuf;          // 16512 B
    float* ssq = (float*)(ldsbuf + 16512);                // 16 B
    const int local = bid - 512;
    const int p = local & 63;
    const int c0 = (local >> 6) * 32;
    const float* sp = proto + ((size_t)p * DIM_ + c0) * HW_;
    float sq = 0.f;
#pragma unroll
    for (int i = 0; i < 4; ++i) {
      int g = i * 256 + t;
      int ci = g >> 5, s4 = g & 31;
      float4 v = *(const float4*)(sp + (size_t)ci * HW_ + s4 * 4);
      sq += v.x * v.x + v.y * v.y + v.z * v.z + v.w * v.w;
      int sb = s4 * 4;
      tile[ci][sb] = v.x; tile[ci][sb + 1] = v.y; tile[ci][sb + 2] = v.z; tile[ci][sb + 3] = v.w;
    }
#pragma unroll
    for (int m = 1; m < 64; m <<= 1) sq += __shfl_xor(sq, m, 64);
    if ((t & 63) == 0) ssq[t >> 6] = sq;
    __syncthreads();
    if (t == 0) pnorm_part[(local >> 6) * PN_ + p] = ssq[0] + ssq[1] + ssq[2] + ssq[3];
    unsigned short* dp = protoT + (size_t)p * HW_ * DIM_ + (size_t)(c0 >> 3) * 1024;
#pragma unroll
    for (int i = 0; i < 2; ++i) {
      int cidx = i * 256 + t;
      int kg = cidx >> 7, s = cidx & 127;
      u16x8 pk;
#pragma unroll
      for (int u = 0; u < 8; ++u) pk[u] = f2bf(tile[kg * 8 + u][s]);
      *(u16x8*)(dp + (size_t)kg * 1024 + (size_t)s * 8) = pk;
    }

  } else {
    // ---------------- cvt role (weights -> k-quad-major bf16) ----------------
    u16x8 (*ctile)[65] = (u16x8 (*)[65])ldsbuf;           // 33280 B
    int local = bid - 4608;
    const float* s; unsigned short* d; int O, CG, tb;
    if (local < 32)       { s = s0; d = d0; O = RF_;  CG = DIM_ / 8; tb = local; }
    else if (local < 352) { s = s1; d = d1; O = DIM_; CG = KMV  / 8; tb = local - 32; }
    else if (local < 608) { s = s2; d = d2; O = DIM_; CG = DIM_ / 8; tb = local - 352; }
    else                  { s = s3; d = d3; O = DIM_; CG = DIM_ / 8; tb = local - 608; }
    const int nCgT = CG / 32;
    const int o0  = (tb / nCgT) * 64;
    const int cg0 = (tb % nCgT) * 32;
    const size_t C = (size_t)CG * 8;

#pragma unroll
    for (int i = 0; i < 8; ++i) {
      int idx = i * 256 + t, ol = idx >> 5, cg = idx & 31;
      const float* sp = s + (size_t)(o0 + ol) * C + (size_t)(cg0 + cg) * 8;
      float4 a = *(const float4*)sp;
      float4 b = *(const float4*)(sp + 4);
      u16x8 pk;
      pk[0] = f2bf(a.x); pk[1] = f2bf(a.y); pk[2] = f2bf(a.z); pk[3] = f2bf(a.w);
      pk[4] = f2bf(b.x); pk[5] = f2bf(b.y); pk[6] = f2bf(b.z); pk[7] = f2bf(b.w);
      ctile[cg][ol] = pk;
    }
    __syncthreads();
#pragma unroll
    for (int i = 0; i < 8; ++i) {
      int idx = i * 256 + t, cg = idx >> 6, ol = idx & 63;
      *(u16x8*)(d + (size_t)(cg0 + cg) * ((size_t)O * 8) + (size_t)(o0 + ol) * 8) =
          ctile[cg][ol];
    }
  }
}

// ---------------------------------------------------------------------------
// select: 512 threads; 8 chunk-groups of 64 lanes sum 64 partial-blocks each
// (4 indep chains), LDS combine, first 64 lanes rank (stable argsort order).
// flags[] pre-zeroed by front; benign same-value race across blocks.
// ---------------------------------------------------------------------------
__global__ __launch_bounds__(512)
void select_kernel(const float* __restrict__ part, const float* __restrict__ pnorm_part,
                   int* __restrict__ idx, int* __restrict__ flags) {
  __shared__ float red[8][64];
  __shared__ float sh[64];
  const int n = blockIdx.x, t = threadIdx.x;
  const int c = t & 63, ch = t >> 6;
  const float* pp = part + (size_t)ch * 64 * 1024 + n * 64 + c;
  float a0 = 0.f, a1 = 0.f, a2 = 0.f, a3 = 0.f;
  for (int b = 0; b < 64; b += 4) {
    a0 += pp[(size_t)(b + 0) * 1024];
    a1 += pp[(size_t)(b + 1) * 1024];
    a2 += pp[(size_t)(b + 2) * 1024];
    a3 += pp[(size_t)(b + 3) * 1024];
  }
  red[ch][c] = (a0 + a1) + (a2 + a3);
  __syncthreads();
  if (t < 64) {
    float pn = 0.f;
#pragma unroll 8
    for (int cb = 0; cb < DIM_ / 32; ++cb) pn += pnorm_part[cb * PN_ + t];
    float dv = pn;
#pragma unroll
    for (int i = 0; i < 8; ++i) dv += red[i][t];
    sh[t] = dv;
  }
  __syncthreads();
  if (t < 64) {
    float dval = sh[t];
    int rank = 0;
#pragma unroll
    for (int j = 0; j < 64; ++j) {
      float o = sh[j];
      rank += (o < dval || (o == dval && j < t)) ? 1 : 0;
    }
    if (rank < TOPK_) { idx[n * TOPK_ + rank] = t; flags[t] = 1; }
  }
}

// ---------------------------------------------------------------------------
// bf16 MFMA GEMM, tile 64Mx128Nx64K. r8: 512 threads = 8 WAVES (r7's 4-wave
// move was confirmed: 43.5 -> ~30us; grid caps blocks/CU at 2, so the
// remaining TLP axis is waves/block again). Wave w owns a 16x64 tile
// (m-quarter = w>>1, n-half = w&1), acc[4] (16 VGPR), 3 staging loads/wave
// (A 1 + B 2), depth-2 prefetch -> counted vmcnt(3). Same tile, traffic, and
// 3-buffer counted-vmcnt pipeline; 16 waves/CU = 4/SIMD.
//
// All staged tensors k-quad-major (W'[kq][O][8], X'[batch][kq][s][8]):
// every global_load_lds reads ONE contiguous 1KB run.
// LDS: A cell(qk,m)=16B @ qk*1024B + m*16B; B cell(qk,n)=qk*2048B + n*16B.
// ---------------------------------------------------------------------------
#define BM 64
#define BKK 64

template <int MODE>
__global__ __launch_bounds__(512, 4)
void mfma_gemm_kernel(const unsigned short* __restrict__ Wb,
                      const unsigned short* __restrict__ Xb,
                      void* __restrict__ OutP,
                      const float* __restrict__ inputs,
                      const int* __restrict__ idxp,
                      const int* __restrict__ flags,
                      int K, int O, int Ldim) {
  __shared__ alignas(16) unsigned short Al[3][8 * BM * 8];    // 3 x 8 KB
  __shared__ alignas(16) unsigned short Bl[3][8 * 128 * 8];   // 3 x 16 KB

  const int t = threadIdx.x;
  const int w = t >> 6;          // wave 0..7
  const int lane = t & 63;
  const int q = lane >> 4;
  const int l15 = lane & 15;
  const int mq = w >> 1;         // m-quarter (16 rows)
  const int h  = w & 1;          // n-half (64 cols)
  const int batch = blockIdx.y;
  const int o0 = blockIdx.x * BM;

  if (MODE == 0 && flags && !flags[batch]) return;

  int idreg = 0;
  if (MODE == 1 && lane < TOPK_) idreg = idxp[batch * TOPK_ + lane];

  f32x4 acc[4] = {};

  auto issue = [&](int k0, int buf) {
    // A: wave w stages k-quad w (one contiguous 1KB load of W'[kq][O][8])
    {
      const unsigned short* ga =
          Wb + (size_t)((k0 >> 3) + w) * (O * 8) + (size_t)(o0 + lane) * 8;
      __builtin_amdgcn_global_load_lds((const AS1 void*)ga,
                                       (AS3 void*)(&Al[buf][w * 512]), 16, 0, 0);
    }
    const unsigned short* base;
    if (MODE == 1) {
      int id = __shfl(idreg, k0 >> 8, 64);
      base = Xb + (size_t)id * (HW_ * RF_) + (size_t)((k0 & 255) >> 3) * 1024;
    } else {
      base = Xb + (size_t)batch * HW_ * K + (size_t)(k0 >> 3) * 1024;
    }
    // B: wave w stages 2 of 16 (qk, half) 1KB regions of X'[kq][s][8].
#pragma unroll
    for (int i = 0; i < 2; ++i) {
      int v = w * 2 + i;
      int qk = v >> 1, hh = v & 1;
      const unsigned short* gb = base + (size_t)qk * 1024 + (size_t)(hh * 64 + lane) * 8;
      __builtin_amdgcn_global_load_lds((const AS1 void*)gb,
                                       (AS3 void*)(&Bl[buf][qk * 1024 + hh * 512]), 16, 0, 0);
    }
  };

  const int nIter = K / BKK;   // 32 (MODE 0/2/3) or 40 (MODE 1)

  issue(0, 0);
  issue(BKK, 1);               // 6 loads/wave outstanding

  for (int it = 0; it < nIter; ++it) {
    const int buf = it % 3;
    // Counted wait: stage-it loads (oldest 3) landed; stage-(it+1) loads
    // stay in flight across the barrier. Full drain only on the last iter.
    if (it + 1 < nIter) {
      asm volatile("s_waitcnt vmcnt(3)" ::: "memory");
    } else {
      asm volatile("s_waitcnt vmcnt(0)" ::: "memory");
    }
    __builtin_amdgcn_s_barrier();
#pragma unroll
    for (int s = 0; s < 2; ++s) {
      bf16x8 af, bfr[4];
      af = *(const bf16x8*)(&Al[buf][(s * 4 + q) * 512 + (mq * 16 + l15) * 8]);
#pragma unroll
      for (int nt = 0; nt < 4; ++nt)
        bfr[nt] = *(const bf16x8*)(&Bl[buf][(s * 4 + q) * 1024 + (h * 64 + nt * 16 + l15) * 8]);
#pragma unroll
      for (int nt = 0; nt < 4; ++nt)
        acc[nt] = __builtin_amdgcn_mfma_f32_16x16x32_bf16(af, bfr[nt], acc[nt], 0, 0, 0);
    }
    if (it + 2 < nIter) issue((it + 2) * BKK, (it + 2) % 3);
  }

  // ---------------- epilogue ----------------
  const float CAL = 1.0f - 1.0f / 262144.0f;

  // MODE2 scratch aliases Al buffer 0 (safe: MODE2's last K-stage uses
  // buffer (31%3)=1, and the final-iter barrier retired all buffer-0 reads).
  float* nsumS = (float*)&Al[0][0];         // [8][16]
  float* nsqS  = (float*)&Al[0][0] + 128;   // [8][16]

  if (MODE == 2) {
#pragma unroll
    for (int reg = 0; reg < 4; ++reg) {
      float s_ = 0.f, q_ = 0.f;
#pragma unroll
      for (int nt = 0; nt < 4; ++nt) {
        float v = acc[nt][reg];
        s_ += v; q_ += v * v;
      }
#pragma unroll
      for (int m = 1; m < 16; m <<= 1) {
        s_ += __shfl_xor(s_, m, 64);
        q_ += __shfl_xor(q_, m, 64);
      }
      if (l15 == 0) {
        nsumS[w * 16 + q * 4 + reg] = s_;
        nsqS [w * 16 + q * 4 + reg] = q_;
      }
    }
    __syncthreads();
  }

  if (MODE == 3) {
    float* ofb = (float*)OutP + (size_t)batch * DIM_ * HW_;
    const float* inb = inputs + (size_t)batch * DIM_ * HW_;
#pragma unroll
    for (int nt = 0; nt < 4; ++nt) {
      int o = o0 + mq * 16 + q * 4;
      int s = h * 64 + nt * 16 + l15;
      f32x4 v = acc[nt];
#pragma unroll
      for (int g = 0; g < 4; ++g) {
        float in = inb[(size_t)(o + g) * HW_ + s];
        float sg = 1.f / (1.f + expf(-v[g]));
        ofb[(size_t)(o + g) * HW_ + s] = in * (1.f + sg);
      }
    }
  } else {
    // Store to X'[batch][o/8][s][8] (k-quad-major): ushort4 at
    // (o>>3)*1024 + s*8 + (o&7); contiguous 256B per 16-lane group.
    unsigned short* ob = (unsigned short*)OutP + (size_t)batch * HW_ * Ldim;
    const float* inb = (MODE == 1) ? inputs + (size_t)batch * DIM_ * HW_ : nullptr;
    float mean[4], rs[4];
    if (MODE == 2) {
#pragma unroll
      for (int reg = 0; reg < 4; ++reg) {
        int ol = q * 4 + reg;
        // combine the two n-half waves of this m-quarter (w = mq*2 + h)
        float ts = nsumS[(mq * 2 + 0) * 16 + ol] + nsumS[(mq * 2 + 1) * 16 + ol];
        float tq = nsqS [(mq * 2 + 0) * 16 + ol] + nsqS [(mq * 2 + 1) * 16 + ol];
        float mn = ts * (1.f / 128.f);
        float vr = tq * (1.f / 128.f) - mn * mn;
        mean[reg] = mn; rs[reg] = rsqrtf(vr + 1e-5f);
      }
    }
#pragma unroll
    for (int nt = 0; nt < 4; ++nt) {
      int o = o0 + mq * 16 + q * 4;
      int s = h * 64 + nt * 16 + l15;
      f32x4 v = acc[nt];
      float r[4];
      if (MODE == 0) {
#pragma unroll
        for (int g = 0; g < 4; ++g) r[g] = v[g];
      } else if (MODE == 1) {
        const float* ip = inb + (size_t)o * HW_ + s;
#pragma unroll
        for (int g = 0; g < 4; ++g)
          r[g] = fmaxf(0.f, 0.5f * ip[(size_t)g * HW_] + CAL * v[g]);
      } else {
#pragma unroll
        for (int g = 0; g < 4; ++g) r[g] = (v[g] - mean[g]) * rs[g];
      }
      ushort4 pk;
      pk.x = f2bf(r[0]); pk.y = f2bf(r[1]); pk.z = f2bf(r[2]); pk.w = f2bf(r[3]);
      *(ushort4*)(ob + (size_t)(o >> 3) * 1024 + (size_t)s * 8 + (o & 7)) = pk;
    }
  }
}

// ---------------------------------------------------------------------------
extern "C" void kernel_launch(void* const* d_in, const int* in_sizes, int n_in,
                              void* d_out, int out_size, void* d_ws, size_t ws_size,
                              hipStream_t stream) {
  const float* inputs = (const float*)d_in[0];
  const float* proto  = (const float*)d_in[1];
  const float* w_rf   = (const float*)d_in[2];
  const float* w_rfmv = (const float*)d_in[3];
  const float* w_rms  = (const float*)d_in[4];
  const float* w_fuse = (const float*)d_in[5];
  float* out = (float*)d_out;

  uint8_t* ws = (uint8_t*)d_ws;
  size_t off = 0;
  auto alloc = [&](size_t bytes) { uint8_t* p = ws + off; off += (bytes + 255) & ~(size_t)255; return p; };

  float* dsum  = (float*)alloc(1088 * 4);       // 4352 B (256-aligned size)
  int*   flags = (int*)alloc(PN_ * 4);          // contiguous after dsum -> zeroed together
  int*   idx   = (int*)alloc(N_ * TOPK_ * 4);
  float* pnorm = (float*)alloc((size_t)(DIM_ / 32) * PN_ * 4);   // 64x64 partials
  float* part  = (float*)alloc((size_t)512 * 1024 * 4);          // 2MB dist partials
  unsigned short* wrf_b   = (unsigned short*)alloc((size_t)RF_ * DIM_ * 2);
  unsigned short* wrfmv_b = (unsigned short*)alloc((size_t)DIM_ * KMV * 2);
  unsigned short* wrms_b  = (unsigned short*)alloc((size_t)DIM_ * DIM_ * 2);
  unsigned short* wfuse_b = (unsigned short*)alloc((size_t)DIM_ * DIM_ * 2);
  unsigned short* xpT     = (unsigned short*)alloc((size_t)PN_ * HW_ * RF_ * 2);
  unsigned short* protoT  = (unsigned short*)alloc((size_t)PN_ * HW_ * DIM_ * 2);
  unsigned short* mvlT = protoT;                 // aliases (protoT dead after G1)
  unsigned short* mvaT = protoT + (size_t)N_ * HW_ * DIM_;

  front_kernel<<<5472, 256, 0, stream>>>(inputs, proto, part, protoT, pnorm,
                                         w_rf, w_rfmv, w_rms, w_fuse,
                                         wrf_b, wrfmv_b, wrms_b, wfuse_b, dsum);
  select_kernel<<<N_, 512, 0, stream>>>(part, pnorm, idx, flags);

  mfma_gemm_kernel<0><<<dim3(RF_ / BM, PN_), 512, 0, stream>>>(
      wrf_b, protoT, xpT, nullptr, nullptr, flags, DIM_, RF_, RF_);
  mfma_gemm_kernel<1><<<dim3(DIM_ / BM, N_), 512, 0, stream>>>(
      wrfmv_b, xpT, mvlT, inputs, idx, nullptr, KMV, DIM_, DIM_);
  mfma_gemm_kernel<2><<<dim3(DIM_ / BM, N_), 512, 0, stream>>>(
      wrms_b, mvlT, mvaT, nullptr, nullptr, nullptr, DIM_, DIM_, DIM_);
  mfma_gemm_kernel<3><<<dim3(DIM_ / BM, N_), 512, 0, stream>>>(
      wfuse_b, mvaT, out, inputs, nullptr, nullptr, DIM_, DIM_, DIM_);
}